// Round 5
// baseline (222.882 us; speedup 1.0000x reference)
//
#include <hip/hip_runtime.h>
#include <stdint.h>

typedef float f32x4 __attribute__((ext_vector_type(4)));
typedef __bf16 bf16x8 __attribute__((ext_vector_type(8)));

#define NN 8192
#define DDIM 128

// Fused TGP kernel, barrier-free K-loop.
// Per 128x128 tile: 4 waves (2x2), each wave owns a 64x64 quadrant.
// Fragments loaded straight from global (L2-resident), RNE hi/lo bf16 split
// in-register (round-3-verified numerics), 3-term MFMA ah.bh+al.bh+ah.bl
// with swapped operands (round-3-verified C layout), norms via lg-axis shfl.
__global__ __launch_bounds__(256, 3) void tgp_kernel(
    const float* __restrict__ X1, const float* __restrict__ X2,
    const float* __restrict__ log_l,
    const float* __restrict__ log_theta_l, const float* __restrict__ bparam,
    const int* __restrict__ task1, const int* __restrict__ task2,
    float* __restrict__ C)
{
    __shared__ float ils[128];
    __shared__ float n1s[128];
    __shared__ float n2s[128];

    const int t = threadIdx.x;
    const int lane = t & 63;
    const int wv = t >> 6;
    const int wr = wv >> 1, wc = wv & 1;
    const int lr = lane & 15, lg = lane >> 4;

    // XCD-aware bijective swizzle (nwg = 4096 = 8*512)
    int wg = blockIdx.x;
    int swz = (wg & 7) * 512 + (wg >> 3);
    int tm = swz >> 6, tn = swz & 63;

    const float* Ag = X1 + (size_t)tm * 128 * DDIM;
    const float* Bg = X2 + (size_t)tn * 128 * DDIM;

    if (t < 128) ils[t] = __expf(-log_l[t]);
    __syncthreads();

    f32x4 acc[4][4];
    #pragma unroll
    for (int i = 0; i < 4; ++i)
        #pragma unroll
        for (int j = 0; j < 4; ++j) acc[i][j] = (f32x4){0.f, 0.f, 0.f, 0.f};

    float nA[4] = {0.f, 0.f, 0.f, 0.f};
    float nB[4] = {0.f, 0.f, 0.f, 0.f};

    #pragma unroll
    for (int c = 0; c < 4; ++c) {
        f32x4 il0 = *(const f32x4*)(ils + c * 32 + lg * 8);
        f32x4 il1 = *(const f32x4*)(ils + c * 32 + lg * 8 + 4);

        bf16x8 ah[4], al[4], bh[4], bl[4];

        #pragma unroll
        for (int mi = 0; mi < 4; ++mi) {
            const float* p = Ag + (size_t)(wr * 64 + mi * 16 + lr) * DDIM + c * 32 + lg * 8;
            f32x4 x0 = *(const f32x4*)p;
            f32x4 x1 = *(const f32x4*)(p + 4);
            x0 *= il0; x1 *= il1;
            nA[mi] += x0[0]*x0[0] + x0[1]*x0[1] + x0[2]*x0[2] + x0[3]*x0[3]
                    + x1[0]*x1[0] + x1[1]*x1[1] + x1[2]*x1[2] + x1[3]*x1[3];
            #pragma unroll
            for (int e = 0; e < 4; ++e) {
                __bf16 h0 = (__bf16)x0[e];
                ah[mi][e] = h0;
                al[mi][e] = (__bf16)(x0[e] - (float)h0);
                __bf16 h1 = (__bf16)x1[e];
                ah[mi][e + 4] = h1;
                al[mi][e + 4] = (__bf16)(x1[e] - (float)h1);
            }
        }
        #pragma unroll
        for (int ni = 0; ni < 4; ++ni) {
            const float* p = Bg + (size_t)(wc * 64 + ni * 16 + lr) * DDIM + c * 32 + lg * 8;
            f32x4 x0 = *(const f32x4*)p;
            f32x4 x1 = *(const f32x4*)(p + 4);
            x0 *= il0; x1 *= il1;
            nB[ni] += x0[0]*x0[0] + x0[1]*x0[1] + x0[2]*x0[2] + x0[3]*x0[3]
                    + x1[0]*x1[0] + x1[1]*x1[1] + x1[2]*x1[2] + x1[3]*x1[3];
            #pragma unroll
            for (int e = 0; e < 4; ++e) {
                __bf16 h0 = (__bf16)x0[e];
                bh[ni][e] = h0;
                bl[ni][e] = (__bf16)(x0[e] - (float)h0);
                __bf16 h1 = (__bf16)x1[e];
                bh[ni][e + 4] = h1;
                bl[ni][e + 4] = (__bf16)(x1[e] - (float)h1);
            }
        }

        #pragma unroll
        for (int mi = 0; mi < 4; ++mi)
            #pragma unroll
            for (int ni = 0; ni < 4; ++ni) {
                acc[mi][ni] = __builtin_amdgcn_mfma_f32_16x16x32_bf16(bh[ni], ah[mi], acc[mi][ni], 0, 0, 0);
                acc[mi][ni] = __builtin_amdgcn_mfma_f32_16x16x32_bf16(bh[ni], al[mi], acc[mi][ni], 0, 0, 0);
                acc[mi][ni] = __builtin_amdgcn_mfma_f32_16x16x32_bf16(bl[ni], ah[mi], acc[mi][ni], 0, 0, 0);
            }
    }

    // ---- norm reduce across lg groups (lanes lr+16*lg hold col-slices) ----
    #pragma unroll
    for (int mi = 0; mi < 4; ++mi) {
        nA[mi] += __shfl_xor(nA[mi], 16);
        nA[mi] += __shfl_xor(nA[mi], 32);
        nB[mi] += __shfl_xor(nB[mi], 16);
        nB[mi] += __shfl_xor(nB[mi], 32);
    }
    if (wc == 0 && lg == 0) {
        #pragma unroll
        for (int mi = 0; mi < 4; ++mi) n1s[wr * 64 + mi * 16 + lr] = nA[mi];
    }
    if (wr == 0 && lg == 0) {
        #pragma unroll
        for (int ni = 0; ni < 4; ++ni) n2s[wc * 64 + ni * 16 + lr] = nB[ni];
    }
    __syncthreads();

    // ---- epilogue (round-3-verified mapping): lane owns row lr-slice,
    //      reg r = 4 consecutive cols at lg*4 (swapped-operand layout) ----
    float logt = log_theta_l[0];
    float bb = bparam[0];
    float lam = fminf(fmaxf(2.f / (1.f + __expf(bb)) - 1.f, 0.f), 1.f);
    int rbase = tm * 128, cbase = tn * 128;

    #pragma unroll
    for (int mi = 0; mi < 4; ++mi) {
        int rowl = wr * 64 + mi * 16 + lr;
        float n1v = n1s[rowl];
        int t1v = task1[rbase + rowl];
        #pragma unroll
        for (int ni = 0; ni < 4; ++ni) {
            int coll = wc * 64 + ni * 16 + lg * 4;
            f32x4 kv;
            #pragma unroll
            for (int r = 0; r < 4; ++r) {
                float n2v = n2s[coll + r];
                int t2v = task2[cbase + coll + r];
                float s = fmaxf(n1v + n2v - 2.f * acc[mi][ni][r], 0.f);
                float k = __expf(fmaf(-0.5f, s, logt));
                kv[r] = (t1v != t2v) ? k * lam : k;
            }
            *(f32x4*)(C + (size_t)(rbase + rowl) * NN + cbase + coll) = kv;
        }
    }
}

extern "C" void kernel_launch(void* const* d_in, const int* in_sizes, int n_in,
                              void* d_out, int out_size, void* d_ws, size_t ws_size,
                              hipStream_t stream)
{
    const float* X1 = (const float*)d_in[0];
    const float* X2 = (const float*)d_in[1];
    const float* log_l = (const float*)d_in[2];
    const float* log_theta = (const float*)d_in[3];
    const float* bp = (const float*)d_in[4];
    const int* t1 = (const int*)d_in[5];
    const int* t2 = (const int*)d_in[6];
    float* C = (float*)d_out;
    (void)d_ws; (void)ws_size; (void)in_sizes; (void)n_in; (void)out_size;

    tgp_kernel<<<4096, 256, 0, stream>>>(X1, X2, log_l, log_theta, bp, t1, t2, C);
}

// Round 6
// 115.253 us; speedup vs baseline: 1.9338x; 1.9338x over previous
//
#include <hip/hip_runtime.h>
#include <stdint.h>

typedef float f32x4 __attribute__((ext_vector_type(4)));
typedef int   i32x4 __attribute__((ext_vector_type(4)));
typedef __bf16 bf16x8 __attribute__((ext_vector_type(8)));

#define NN 8192
#define DDIM 128
#define RSTRIDE 80   // padded LDS row stride (32 bf16 = 64 B) + 16 B pad

// LDS byte offsets (single-buffered split tiles)
#define OFF_AH 0
#define OFF_AL 10240
#define OFF_BH 20480
#define OFF_BL 30720
#define OFF_ILS 40960
#define OFF_N1  41472
#define OFF_N2  41984
#define LDS_TOT 42496

__device__ __forceinline__ uint32_t pk2(__bf16 a, __bf16 b) {
    return (uint32_t)__builtin_bit_cast(unsigned short, a)
         | ((uint32_t)__builtin_bit_cast(unsigned short, b) << 16);
}

// RNE hi/lo split of 4 scaled f32 (round-3/5-verified numerics)
__device__ __forceinline__ void split4(f32x4 x, uint2& hi, uint2& lo) {
    __bf16 h0 = (__bf16)x[0], h1 = (__bf16)x[1], h2 = (__bf16)x[2], h3 = (__bf16)x[3];
    hi.x = pk2(h0, h1); hi.y = pk2(h2, h3);
    __bf16 l0 = (__bf16)(x[0] - (float)h0);
    __bf16 l1 = (__bf16)(x[1] - (float)h1);
    __bf16 l2 = (__bf16)(x[2] - (float)h2);
    __bf16 l3 = (__bf16)(x[3] - (float)h3);
    lo.x = pk2(l0, l1); lo.y = pk2(l2, l3);
}

// Fused TGP: split-once-to-LDS bf16 3-term GEMM + in-LDS norms + fused epilogue.
// 128x128 tile, 2x2 waves of 64x64. Single-buffered tiles, 2 barriers/chunk
// (classic sync-write-sync-read; no dbuf, no swizzle -> padded stride).
__global__ __launch_bounds__(256, 3) void tgp_kernel(
    const float* __restrict__ X1, const float* __restrict__ X2,
    const float* __restrict__ log_l,
    const float* __restrict__ log_theta_l, const float* __restrict__ bparam,
    const int* __restrict__ task1, const int* __restrict__ task2,
    float* __restrict__ C)
{
    __shared__ __align__(16) char smem[LDS_TOT];
    float* const ils = (float*)(smem + OFF_ILS);
    float* const n1s = (float*)(smem + OFF_N1);
    float* const n2s = (float*)(smem + OFF_N2);

    const int t = threadIdx.x;
    const int lane = t & 63;
    const int wv = t >> 6;
    const int wr = wv >> 1, wc = wv & 1;
    const int lr = lane & 15, lg = lane >> 4;
    const int kq = t & 7;     // 4-col group within 32-col chunk
    const int rg = t >> 3;    // row within each 32-row e-stripe

    // XCD-aware bijective swizzle (nwg = 4096 = 8*512)
    int wg = blockIdx.x;
    int swz = (wg & 7) * 512 + (wg >> 3);
    int tm = swz >> 6, tn = swz & 63;

    const float* Ag = X1 + (size_t)tm * 128 * DDIM;
    const float* Bg = X2 + (size_t)tn * 128 * DDIM;

    if (t < 128) ils[t] = __expf(-log_l[t]);

    f32x4 aV[4], bV[4];
    #pragma unroll
    for (int e = 0; e < 4; ++e) {
        aV[e] = *(const f32x4*)(Ag + (size_t)(e * 32 + rg) * DDIM + kq * 4);
        bV[e] = *(const f32x4*)(Bg + (size_t)(e * 32 + rg) * DDIM + kq * 4);
    }
    __syncthreads();   // ils visible

    float nA[4] = {0.f, 0.f, 0.f, 0.f};
    float nB[4] = {0.f, 0.f, 0.f, 0.f};
    f32x4 acc[4][4];
    #pragma unroll
    for (int i = 0; i < 4; ++i)
        #pragma unroll
        for (int j = 0; j < 4; ++j) acc[i][j] = (f32x4){0.f, 0.f, 0.f, 0.f};

    for (int c = 0; c < 4; ++c) {
        // ---- split-write: scale, norm partial, RNE hi/lo, padded ds_write ----
        f32x4 il4 = *(const f32x4*)(ils + c * 32 + kq * 4);
        #pragma unroll
        for (int e = 0; e < 4; ++e) {
            int r = e * 32 + rg;
            f32x4 xa = aV[e] * il4;
            f32x4 xb = bV[e] * il4;
            nA[e] += xa[0]*xa[0] + xa[1]*xa[1] + xa[2]*xa[2] + xa[3]*xa[3];
            nB[e] += xb[0]*xb[0] + xb[1]*xb[1] + xb[2]*xb[2] + xb[3]*xb[3];
            uint2 hA, lA, hB, lB;
            split4(xa, hA, lA);
            split4(xb, hB, lB);
            int boff = r * RSTRIDE + kq * 8;
            *(uint2*)(smem + OFF_AH + boff) = hA;
            *(uint2*)(smem + OFF_AL + boff) = lA;
            *(uint2*)(smem + OFF_BH + boff) = hB;
            *(uint2*)(smem + OFF_BL + boff) = lB;
        }
        // T14: issue next chunk's global loads before the barrier+MFMA
        if (c < 3) {
            #pragma unroll
            for (int e = 0; e < 4; ++e) {
                aV[e] = *(const f32x4*)(Ag + (size_t)(e * 32 + rg) * DDIM + (c + 1) * 32 + kq * 4);
                bV[e] = *(const f32x4*)(Bg + (size_t)(e * 32 + rg) * DDIM + (c + 1) * 32 + kq * 4);
            }
        }
        __syncthreads();   // split tiles visible

        // ---- fragment reads + 48 MFMA (3-term, swapped operands) ----
        {
            bf16x8 ah[4], bh[4], xf[4];
            #pragma unroll
            for (int mi = 0; mi < 4; ++mi) {
                int off = (wr * 64 + mi * 16 + lr) * RSTRIDE + lg * 16;
                ah[mi] = *(const bf16x8*)(smem + OFF_AH + off);
            }
            #pragma unroll
            for (int ni = 0; ni < 4; ++ni) {
                int off = (wc * 64 + ni * 16 + lr) * RSTRIDE + lg * 16;
                bh[ni] = *(const bf16x8*)(smem + OFF_BH + off);
            }
            #pragma unroll
            for (int mi = 0; mi < 4; ++mi)
                #pragma unroll
                for (int ni = 0; ni < 4; ++ni)
                    acc[mi][ni] = __builtin_amdgcn_mfma_f32_16x16x32_bf16(bh[ni], ah[mi], acc[mi][ni], 0, 0, 0);
            // lo(A) x hi(B)
            #pragma unroll
            for (int mi = 0; mi < 4; ++mi) {
                int off = (wr * 64 + mi * 16 + lr) * RSTRIDE + lg * 16;
                xf[mi] = *(const bf16x8*)(smem + OFF_AL + off);
            }
            #pragma unroll
            for (int mi = 0; mi < 4; ++mi)
                #pragma unroll
                for (int ni = 0; ni < 4; ++ni)
                    acc[mi][ni] = __builtin_amdgcn_mfma_f32_16x16x32_bf16(bh[ni], xf[mi], acc[mi][ni], 0, 0, 0);
            // hi(A) x lo(B)
            #pragma unroll
            for (int ni = 0; ni < 4; ++ni) {
                int off = (wc * 64 + ni * 16 + lr) * RSTRIDE + lg * 16;
                xf[ni] = *(const bf16x8*)(smem + OFF_BL + off);
            }
            #pragma unroll
            for (int mi = 0; mi < 4; ++mi)
                #pragma unroll
                for (int ni = 0; ni < 4; ++ni)
                    acc[mi][ni] = __builtin_amdgcn_mfma_f32_16x16x32_bf16(xf[ni], ah[mi], acc[mi][ni], 0, 0, 0);
        }
        __syncthreads();   // reads done before next chunk overwrites tiles
    }

    // ---- norm reduce: 8-lane groups (lanes share rg, kq spans cols) ----
    #pragma unroll
    for (int e = 0; e < 4; ++e) {
        #pragma unroll
        for (int off = 1; off < 8; off <<= 1) {
            nA[e] += __shfl_xor(nA[e], off);
            nB[e] += __shfl_xor(nB[e], off);
        }
    }
    if ((t & 7) == 0) {
        #pragma unroll
        for (int e = 0; e < 4; ++e) {
            n1s[e * 32 + rg] = nA[e];
            n2s[e * 32 + rg] = nB[e];
        }
    }
    __syncthreads();

    // ---- epilogue (round-5-verified mapping): lane lr = A-row slice,
    //      reg r = 4 consecutive cols at lg*4 (swapped operands) ----
    float logt = log_theta_l[0];
    float bb = bparam[0];
    float lam = fminf(fmaxf(2.f / (1.f + __expf(bb)) - 1.f, 0.f), 1.f);
    int rbase = tm * 128, cbase = tn * 128;

    #pragma unroll
    for (int mi = 0; mi < 4; ++mi) {
        int rowl = wr * 64 + mi * 16 + lr;
        float n1v = n1s[rowl];
        int t1v = task1[rbase + rowl];
        #pragma unroll
        for (int ni = 0; ni < 4; ++ni) {
            int coll = wc * 64 + ni * 16 + lg * 4;
            f32x4 n2v = *(const f32x4*)(n2s + coll);
            i32x4 t2v = *(const i32x4*)(task2 + cbase + coll);
            f32x4 kv;
            #pragma unroll
            for (int r = 0; r < 4; ++r) {
                float s = fmaxf(n1v + n2v[r] - 2.f * acc[mi][ni][r], 0.f);
                float k = __expf(fmaf(-0.5f, s, logt));
                kv[r] = (t1v != t2v[r]) ? k * lam : k;
            }
            *(f32x4*)(C + (size_t)(rbase + rowl) * NN + cbase + coll) = kv;
        }
    }
}

extern "C" void kernel_launch(void* const* d_in, const int* in_sizes, int n_in,
                              void* d_out, int out_size, void* d_ws, size_t ws_size,
                              hipStream_t stream)
{
    const float* X1 = (const float*)d_in[0];
    const float* X2 = (const float*)d_in[1];
    const float* log_l = (const float*)d_in[2];
    const float* log_theta = (const float*)d_in[3];
    const float* bp = (const float*)d_in[4];
    const int* t1 = (const int*)d_in[5];
    const int* t2 = (const int*)d_in[6];
    float* C = (float*)d_out;
    (void)d_ws; (void)ws_size; (void)in_sizes; (void)n_in; (void)out_size;

    tgp_kernel<<<4096, 256, 0, stream>>>(X1, X2, log_l, log_theta, bp, t1, t2, C);
}

// Round 7
// 98.619 us; speedup vs baseline: 2.2600x; 1.1687x over previous
//
#include <hip/hip_runtime.h>
#include <stdint.h>

typedef float f32x4 __attribute__((ext_vector_type(4)));
typedef int   i32x4 __attribute__((ext_vector_type(4)));
typedef __bf16 bf16x8 __attribute__((ext_vector_type(8)));

#define NN 8192
#define DDIM 128
#define RSTRIDE 80   // padded LDS row stride (32 bf16 = 64 B) + 16 B pad

// LDS byte offsets (single-buffered split tiles)
#define OFF_AH 0
#define OFF_AL 10240
#define OFF_BH 20480
#define OFF_BL 30720
#define OFF_ILS 40960
#define OFF_N1  41472
#define OFF_N2  41984
#define LDS_TOT 42496

__device__ __forceinline__ uint32_t pk2(__bf16 a, __bf16 b) {
    return (uint32_t)__builtin_bit_cast(unsigned short, a)
         | ((uint32_t)__builtin_bit_cast(unsigned short, b) << 16);
}

// RNE hi/lo split of 4 scaled f32 (round-3/5/6-verified numerics)
__device__ __forceinline__ void split4(f32x4 x, uint2& hi, uint2& lo) {
    __bf16 h0 = (__bf16)x[0], h1 = (__bf16)x[1], h2 = (__bf16)x[2], h3 = (__bf16)x[3];
    hi.x = pk2(h0, h1); hi.y = pk2(h2, h3);
    __bf16 l0 = (__bf16)(x[0] - (float)h0);
    __bf16 l1 = (__bf16)(x[1] - (float)h1);
    __bf16 l2 = (__bf16)(x[2] - (float)h2);
    __bf16 l3 = (__bf16)(x[3] - (float)h3);
    lo.x = pk2(l0, l1); lo.y = pk2(l2, l3);
}

// Barrier that does NOT drain vmcnt: LDS-visibility only, order-pinned
// (rule #18: sched_barrier after the waitcnt so nothing is hoisted across).
__device__ __forceinline__ void lds_barrier() {
    asm volatile("s_waitcnt lgkmcnt(0)" ::: "memory");
    __builtin_amdgcn_sched_barrier(0);
    __builtin_amdgcn_s_barrier();
    __builtin_amdgcn_sched_barrier(0);
}

// Fused TGP: split-once-to-LDS bf16 3-term GEMM + in-LDS norms + fused epilogue.
// 128x128 tile, 2x2 waves of 64x64. Single-buffered tiles, 2 LDS-barriers/chunk;
// global prefetch for chunk c+1 stays in flight across both barriers (T4 spirit).
__global__ __launch_bounds__(256, 3) void tgp_kernel(
    const float* __restrict__ X1, const float* __restrict__ X2,
    const float* __restrict__ log_l,
    const float* __restrict__ log_theta_l, const float* __restrict__ bparam,
    const int* __restrict__ task1, const int* __restrict__ task2,
    float* __restrict__ C)
{
    __shared__ __align__(16) char smem[LDS_TOT];
    float* const ils = (float*)(smem + OFF_ILS);
    float* const n1s = (float*)(smem + OFF_N1);
    float* const n2s = (float*)(smem + OFF_N2);

    const int t = threadIdx.x;
    const int lane = t & 63;
    const int wv = t >> 6;
    const int wr = wv >> 1, wc = wv & 1;
    const int lr = lane & 15, lg = lane >> 4;
    const int kq = t & 7;     // 4-col group within 32-col chunk
    const int rg = t >> 3;    // row within each 32-row e-stripe

    // L2 super-tile ordering: XCD x owns A-row band x (512 KB, stays hot in
    // its L2) and sweeps B in 8-tile (512 KB) super-columns. Bijective:
    // wg = (xcd, su, inner) <-> (tm, tn).
    int wg = blockIdx.x;
    int xcd = wg & 7;
    int r = wg >> 3;            // 0..511 within XCD
    int su = r >> 6;            // 0..7 super-column
    int inner = r & 63;         // 8x8 tiles within super-tile
    int tm = xcd * 8 + (inner >> 3);
    int tn = su * 8 + (inner & 7);

    const float* Ag = X1 + (size_t)tm * 128 * DDIM;
    const float* Bg = X2 + (size_t)tn * 128 * DDIM;

    if (t < 128) ils[t] = __expf(-log_l[t]);

    f32x4 aV[4], bV[4];
    #pragma unroll
    for (int e = 0; e < 4; ++e) {
        aV[e] = *(const f32x4*)(Ag + (size_t)(e * 32 + rg) * DDIM + kq * 4);
        bV[e] = *(const f32x4*)(Bg + (size_t)(e * 32 + rg) * DDIM + kq * 4);
    }
    __syncthreads();   // ils visible (full barrier, once)

    float nA[4] = {0.f, 0.f, 0.f, 0.f};
    float nB[4] = {0.f, 0.f, 0.f, 0.f};
    f32x4 acc[4][4];
    #pragma unroll
    for (int i = 0; i < 4; ++i)
        #pragma unroll
        for (int j = 0; j < 4; ++j) acc[i][j] = (f32x4){0.f, 0.f, 0.f, 0.f};

    for (int c = 0; c < 4; ++c) {
        // ---- split-write: scale, norm partial, RNE hi/lo, padded ds_write ----
        f32x4 il4 = *(const f32x4*)(ils + c * 32 + kq * 4);
        #pragma unroll
        for (int e = 0; e < 4; ++e) {
            int rr = e * 32 + rg;
            f32x4 xa = aV[e] * il4;
            f32x4 xb = bV[e] * il4;
            nA[e] += xa[0]*xa[0] + xa[1]*xa[1] + xa[2]*xa[2] + xa[3]*xa[3];
            nB[e] += xb[0]*xb[0] + xb[1]*xb[1] + xb[2]*xb[2] + xb[3]*xb[3];
            uint2 hA, lA, hB, lB;
            split4(xa, hA, lA);
            split4(xb, hB, lB);
            int boff = rr * RSTRIDE + kq * 8;
            *(uint2*)(smem + OFF_AH + boff) = hA;
            *(uint2*)(smem + OFF_AL + boff) = lA;
            *(uint2*)(smem + OFF_BH + boff) = hB;
            *(uint2*)(smem + OFF_BL + boff) = lB;
        }
        // T14: issue next chunk's global loads; they stay IN FLIGHT across the
        // lds_barriers below (no vmcnt drain) and are waited only at next use.
        if (c < 3) {
            #pragma unroll
            for (int e = 0; e < 4; ++e) {
                aV[e] = *(const f32x4*)(Ag + (size_t)(e * 32 + rg) * DDIM + (c + 1) * 32 + kq * 4);
                bV[e] = *(const f32x4*)(Bg + (size_t)(e * 32 + rg) * DDIM + (c + 1) * 32 + kq * 4);
            }
        }
        lds_barrier();   // split tiles visible; global prefetch NOT drained

        // ---- fragment reads + 48 MFMA (3-term, swapped operands) ----
        {
            bf16x8 ah[4], bh[4], xf[4];
            #pragma unroll
            for (int mi = 0; mi < 4; ++mi) {
                int off = (wr * 64 + mi * 16 + lr) * RSTRIDE + lg * 16;
                ah[mi] = *(const bf16x8*)(smem + OFF_AH + off);
            }
            #pragma unroll
            for (int ni = 0; ni < 4; ++ni) {
                int off = (wc * 64 + ni * 16 + lr) * RSTRIDE + lg * 16;
                bh[ni] = *(const bf16x8*)(smem + OFF_BH + off);
            }
            #pragma unroll
            for (int mi = 0; mi < 4; ++mi)
                #pragma unroll
                for (int ni = 0; ni < 4; ++ni)
                    acc[mi][ni] = __builtin_amdgcn_mfma_f32_16x16x32_bf16(bh[ni], ah[mi], acc[mi][ni], 0, 0, 0);
            // lo(A) x hi(B)
            #pragma unroll
            for (int mi = 0; mi < 4; ++mi) {
                int off = (wr * 64 + mi * 16 + lr) * RSTRIDE + lg * 16;
                xf[mi] = *(const bf16x8*)(smem + OFF_AL + off);
            }
            #pragma unroll
            for (int mi = 0; mi < 4; ++mi)
                #pragma unroll
                for (int ni = 0; ni < 4; ++ni)
                    acc[mi][ni] = __builtin_amdgcn_mfma_f32_16x16x32_bf16(bh[ni], xf[mi], acc[mi][ni], 0, 0, 0);
            // hi(A) x lo(B)
            #pragma unroll
            for (int ni = 0; ni < 4; ++ni) {
                int off = (wc * 64 + ni * 16 + lr) * RSTRIDE + lg * 16;
                xf[ni] = *(const bf16x8*)(smem + OFF_BL + off);
            }
            #pragma unroll
            for (int mi = 0; mi < 4; ++mi)
                #pragma unroll
                for (int ni = 0; ni < 4; ++ni)
                    acc[mi][ni] = __builtin_amdgcn_mfma_f32_16x16x32_bf16(xf[ni], ah[mi], acc[mi][ni], 0, 0, 0);
        }
        lds_barrier();   // all reads done before next chunk overwrites tiles
    }

    // ---- norm reduce: 8-lane groups (lanes share rg, kq spans cols) ----
    #pragma unroll
    for (int e = 0; e < 4; ++e) {
        #pragma unroll
        for (int off = 1; off < 8; off <<= 1) {
            nA[e] += __shfl_xor(nA[e], off);
            nB[e] += __shfl_xor(nB[e], off);
        }
    }
    if ((t & 7) == 0) {
        #pragma unroll
        for (int e = 0; e < 4; ++e) {
            n1s[e * 32 + rg] = nA[e];
            n2s[e * 32 + rg] = nB[e];
        }
    }
    __syncthreads();   // norms visible (full barrier, once)

    // ---- epilogue (verified mapping): lane lr = A-row slice,
    //      reg r = 4 consecutive cols at lg*4 (swapped operands) ----
    float logt = log_theta_l[0];
    float bb = bparam[0];
    float lam = fminf(fmaxf(2.f / (1.f + __expf(bb)) - 1.f, 0.f), 1.f);
    int rbase = tm * 128, cbase = tn * 128;

    #pragma unroll
    for (int mi = 0; mi < 4; ++mi) {
        int rowl = wr * 64 + mi * 16 + lr;
        float n1v = n1s[rowl];
        int t1v = task1[rbase + rowl];
        #pragma unroll
        for (int ni = 0; ni < 4; ++ni) {
            int coll = wc * 64 + ni * 16 + lg * 4;
            f32x4 n2v = *(const f32x4*)(n2s + coll);
            i32x4 t2v = *(const i32x4*)(task2 + cbase + coll);
            f32x4 kv;
            #pragma unroll
            for (int rix = 0; rix < 4; ++rix) {
                float s = fmaxf(n1v + n2v[rix] - 2.f * acc[mi][ni][rix], 0.f);
                float k = __expf(fmaf(-0.5f, s, logt));
                kv[rix] = (t1v != t2v[rix]) ? k * lam : k;
            }
            *(f32x4*)(C + (size_t)(rbase + rowl) * NN + cbase + coll) = kv;
        }
    }
}

extern "C" void kernel_launch(void* const* d_in, const int* in_sizes, int n_in,
                              void* d_out, int out_size, void* d_ws, size_t ws_size,
                              hipStream_t stream)
{
    const float* X1 = (const float*)d_in[0];
    const float* X2 = (const float*)d_in[1];
    const float* log_l = (const float*)d_in[2];
    const float* log_theta = (const float*)d_in[3];
    const float* bp = (const float*)d_in[4];
    const int* t1 = (const int*)d_in[5];
    const int* t2 = (const int*)d_in[6];
    float* C = (float*)d_out;
    (void)d_ws; (void)ws_size; (void)in_sizes; (void)n_in; (void)out_size;

    tgp_kernel<<<4096, 256, 0, stream>>>(X1, X2, log_l, log_theta, bp, t1, t2, C);
}